// Round 11
// baseline (324.822 us; speedup 1.0000x reference)
//
#include <hip/hip_runtime.h>
#include <stdint.h>

typedef unsigned short ushort_t;
typedef short bf16x8 __attribute__((ext_vector_type(8)));
typedef short s16x2 __attribute__((ext_vector_type(2)));
typedef float f32x4 __attribute__((ext_vector_type(4)));
typedef ushort_t us2 __attribute__((ext_vector_type(2)));
typedef ushort_t us4 __attribute__((ext_vector_type(4)));
typedef ushort_t us8 __attribute__((ext_vector_type(8)));

__device__ __forceinline__ float b2f(ushort_t u) {
    union { unsigned int i; float f; } v; v.i = ((unsigned int)u) << 16; return v.f;
}
__device__ __forceinline__ ushort_t f2b(float f) {
    union { float f; unsigned int i; } v; v.f = f;
    unsigned int r = v.i + 0x7fffu + ((v.i >> 16) & 1u);
    return (ushort_t)(r >> 16);
}

#if __has_builtin(__builtin_amdgcn_exp2f)
#define EXP2F(x) __builtin_amdgcn_exp2f(x)
#else
#define EXP2F(x) exp2f(x)
#endif

typedef __attribute__((address_space(3))) unsigned int lds_u32;
typedef __attribute__((address_space(1))) const unsigned int gbl_u32;

__device__ __forceinline__ void gload_lds16(const void* g, void* l) {
    __builtin_amdgcn_global_load_lds((gbl_u32*)g, (lds_u32*)l, 16, 0, 0);
}

// ---------------------------------------------------------------------------
// fp32 -> bf16 elementwise convert, 8 elems/thread, THREE buffers fused into
// one launch (hs | qkv_w | proj_w): 7200 blocks x 256 thr.
// ---------------------------------------------------------------------------
__global__ void cvt3_f32_bf16(const float* __restrict__ s0, ushort_t* __restrict__ d0, int n0,
                              const float* __restrict__ s1, ushort_t* __restrict__ d1, int n1,
                              const float* __restrict__ s2, ushort_t* __restrict__ d2, int n2)
{
    int i = blockIdx.x * 256 + threadIdx.x;
    const float* s; ushort_t* d; int j;
    if (i < n0)           { s = s0; d = d0; j = i; }
    else if (i < n0 + n1) { s = s1; d = d1; j = i - n0; }
    else if (i < n0 + n1 + n2) { s = s2; d = d2; j = i - n0 - n1; }
    else return;
    f32x4 a = *(const f32x4*)&s[(size_t)j * 8];
    f32x4 b = *(const f32x4*)&s[(size_t)j * 8 + 4];
    us8 o;
#pragma unroll
    for (int k = 0; k < 4; k++) { o[k] = f2b(a[k]); o[k + 4] = f2b(b[k]); }
    *(us8*)&d[(size_t)j * 8] = o;
}

// ---------------------------------------------------------------------------
// gemm256 v5: C = A @ B^T + bias.  256x256 tile, BK=64, 512 thr (8 waves
// 2Mx4N, per-wave 128x64), double-buffered 128 KiB LDS.
// v5 = v2 with the m201 phase shape: per phase {reads; stage; BARRIER;
// lgkmcnt(0); MFMA x16; BARRIER} -- reads fully drained before the MFMA
// cluster, two barriers/phase (m201's verified 62%-MfmaUtil schedule).
// Read distribution 10/6/8/0 and staging order byte-identical to v2:
//   ph0: reads a0[8]+bk0[0,1]; stage A0(kt+1) [non-live]
//   ph1: reads bk0[2,3]+bk1[0..3]; stage A1(kt+1) [non-live]
//   ph2: reads a1[8]; stage B0(kt+2) [live-B: all B-reads drained by each
//        wave's ph1 lgkm(0), end-barrier passed -> safe]
//   ph3: no reads; stage B1(kt+2); counted vmcnt(4) (vmcnt(0) last two kt)
// OUT_F32=false: bf16 C, swizzled LDS-staged us8 stores.
// OUT_F32=true : f32 C, two half-tile LDS passes, window-XOR (nf^qd).
// N need not divide 256: overreads land in mapped ws; stores masked.
// History: v1(2bar,16/0/8/0)=85.7, v2(1bar,10/6/8/0)=78-79, v3(prefetch,
// lgkm0-drains-it)=82.4, v4(2phase,24/0 burst)=88.4.
// ---------------------------------------------------------------------------
template <bool OUT_F32>
__global__ __launch_bounds__(512, 2) void gemm256_bt_bias(
    const ushort_t* __restrict__ A, const ushort_t* __restrict__ B,
    const float* __restrict__ bias, void* __restrict__ Cv,
    int K, int Npitch, int Nvalid)
{
    __shared__ short Sm[65536];   // 128 KiB: buf{0,1} x [A 256x64 | B 256x64]

    const int t = threadIdx.x;
    const int lane = t & 63, w = t >> 6;
    const int qd = lane >> 4, ln = lane & 15;
    const int wm = w >> 2, wn = w & 3;

    // XCD-aware bijective swizzle (grid size % 8 == 0 for both uses)
    const int nwgx = gridDim.x;
    const int bid = blockIdx.y * nwgx + blockIdx.x;
    const int q8 = (nwgx * gridDim.y) >> 3;
    const int swz = (bid & 7) * q8 + (bid >> 3);
    const int m0 = (swz / nwgx) * 256, n0 = (swz % nwgx) * 256;

    const int NT = K >> 6;   // number of 64-wide K-tiles
    const int H4 = K >> 4;   // total half-tiles (4 per K-tile)

    const int sr = t >> 3, sc = t & 7;
    const int csw = (sc ^ (sr & 7)) * 8;
    const ushort_t* pA = A + (size_t)(m0 + sr) * K + csw;
    const ushort_t* pB = B + (size_t)(n0 + sr) * K + csw;
    const size_t rowK64 = (size_t)64 * K;
    const size_t rowK128 = (size_t)128 * K;

    auto stage = [&](int h) {
        if (h >= H4) return;
        const int ktt = h >> 2, reg = h & 3;
        const ushort_t* s0;
        int lo;
        if (reg == 0)      { s0 = pB;           lo = 16384; }
        else if (reg == 1) { s0 = pB + rowK128; lo = 24576; }
        else if (reg == 2) { s0 = pA;           lo = 0;     }
        else               { s0 = pA + rowK128; lo = 8192;  }
        short* d = &Sm[(ktt & 1) * 32768 + lo + t * 8];
        const ushort_t* g = s0 + (size_t)ktt * 64;
        gload_lds16(g, d);                       // rows 0..63 of half-tile
        gload_lds16(g + rowK64, d + 4096);       // rows 64..127
    };

    f32x4 acc[8][4];
#pragma unroll
    for (int i = 0; i < 8; i++)
#pragma unroll
        for (int j = 0; j < 4; j++) acc[i][j] = (f32x4){0.f, 0.f, 0.f, 0.f};

    const int pc0 = (qd ^ (ln & 7)) * 8;
    const int pc1 = ((4 + qd) ^ (ln & 7)) * 8;
    const int arow = wm * 128 + ln;
    const int brow = wn * 64 + ln;

    // ---- prologue: half-tiles 0..5 (kt0 complete + B0,B1 of kt1) ----
#pragma unroll
    for (int h = 0; h < 6; h++) stage(h);
    asm volatile("s_waitcnt vmcnt(4)" ::: "memory");
    __builtin_amdgcn_s_barrier();

    for (int kt = 0; kt < NT; kt++) {
        const int buf = (kt & 1) * 32768;
        const short* Ab = &Sm[buf];
        const short* Bb = &Sm[buf + 16384];
        const int p = kt * 4;

        bf16x8 a[8], bk0[4], bk1[4];

        // ---- phase 0: reads a0[8]+bk0[0,1]; stage A0(kt+1); bar; MFMA x16
#pragma unroll
        for (int mf = 0; mf < 8; mf++)
            a[mf] = *(const bf16x8*)&Ab[(arow + mf * 16) * 64 + pc0];
        bk0[0] = *(const bf16x8*)&Bb[(brow + 0)  * 64 + pc0];
        bk0[1] = *(const bf16x8*)&Bb[(brow + 16) * 64 + pc0];
        stage(p + 6);
        __builtin_amdgcn_s_barrier();
        asm volatile("s_waitcnt lgkmcnt(0)" ::: "memory");
        __builtin_amdgcn_s_setprio(1);
#pragma unroll
        for (int mf = 0; mf < 8; mf++) {
            acc[mf][0] = __builtin_amdgcn_mfma_f32_16x16x32_bf16(a[mf], bk0[0], acc[mf][0], 0, 0, 0);
            acc[mf][1] = __builtin_amdgcn_mfma_f32_16x16x32_bf16(a[mf], bk0[1], acc[mf][1], 0, 0, 0);
        }
        __builtin_amdgcn_s_setprio(0);
        __builtin_amdgcn_s_barrier();

        // ---- phase 1: reads bk0[2,3]+bk1[0..3]; stage A1(kt+1); bar; MFMA
        bk0[2] = *(const bf16x8*)&Bb[(brow + 32) * 64 + pc0];
        bk0[3] = *(const bf16x8*)&Bb[(brow + 48) * 64 + pc0];
#pragma unroll
        for (int nf = 0; nf < 4; nf++)
            bk1[nf] = *(const bf16x8*)&Bb[(brow + nf * 16) * 64 + pc1];
        stage(p + 7);
        __builtin_amdgcn_s_barrier();
        asm volatile("s_waitcnt lgkmcnt(0)" ::: "memory");
        __builtin_amdgcn_s_setprio(1);
#pragma unroll
        for (int mf = 0; mf < 8; mf++) {
            acc[mf][2] = __builtin_amdgcn_mfma_f32_16x16x32_bf16(a[mf], bk0[2], acc[mf][2], 0, 0, 0);
            acc[mf][3] = __builtin_amdgcn_mfma_f32_16x16x32_bf16(a[mf], bk0[3], acc[mf][3], 0, 0, 0);
        }
        __builtin_amdgcn_s_setprio(0);
        __builtin_amdgcn_s_barrier();

        // ---- phase 2: reads a1[8]; stage B0(kt+2); bar; MFMA x16
#pragma unroll
        for (int mf = 0; mf < 8; mf++)
            a[mf] = *(const bf16x8*)&Ab[(arow + mf * 16) * 64 + pc1];
        stage(p + 8);
        __builtin_amdgcn_s_barrier();
        asm volatile("s_waitcnt lgkmcnt(0)" ::: "memory");
        __builtin_amdgcn_s_setprio(1);
#pragma unroll
        for (int mf = 0; mf < 8; mf++) {
            acc[mf][0] = __builtin_amdgcn_mfma_f32_16x16x32_bf16(a[mf], bk1[0], acc[mf][0], 0, 0, 0);
            acc[mf][1] = __builtin_amdgcn_mfma_f32_16x16x32_bf16(a[mf], bk1[1], acc[mf][1], 0, 0, 0);
        }
        __builtin_amdgcn_s_setprio(0);
        __builtin_amdgcn_s_barrier();

        // ---- phase 3: stage B1(kt+2); bar; MFMA x16; counted vmcnt; bar
        stage(p + 9);
        __builtin_amdgcn_s_barrier();
        asm volatile("s_waitcnt lgkmcnt(0)" ::: "memory");
        __builtin_amdgcn_s_setprio(1);
#pragma unroll
        for (int mf = 0; mf < 8; mf++) {
            acc[mf][2] = __builtin_amdgcn_mfma_f32_16x16x32_bf16(a[mf], bk1[2], acc[mf][2], 0, 0, 0);
            acc[mf][3] = __builtin_amdgcn_mfma_f32_16x16x32_bf16(a[mf], bk1[3], acc[mf][3], 0, 0, 0);
        }
        __builtin_amdgcn_s_setprio(0);
        if (kt < NT - 2) { asm volatile("s_waitcnt vmcnt(4)" ::: "memory"); }
        else             { asm volatile("s_waitcnt vmcnt(0)" ::: "memory"); }
        __builtin_amdgcn_s_barrier();
    }

    // ---- epilogue ----
    __syncthreads();
    float bv[4];
#pragma unroll
    for (int nf = 0; nf < 4; nf++) {
        const int gc = n0 + wn * 64 + nf * 16 + ln;
        bv[nf] = (gc < Nvalid) ? bias[gc] : 0.f;
    }

    if (!OUT_F32) {
        ushort_t* C = (ushort_t*)Cv;
        char* Smb = (char*)Sm;
#pragma unroll
        for (int mf = 0; mf < 8; mf++) {
            const int row = wm * 128 + mf * 16 + qd * 4;
#pragma unroll
            for (int nf = 0; nf < 4; nf++) {
                const int swc = ((wn * 64 + nf * 16 + ln) * 2) ^ (qd << 5);
#pragma unroll
                for (int r = 0; r < 4; r++)
                    *(ushort_t*)(Smb + (row + r) * 512 + swc) = f2b(acc[mf][nf][r] + bv[nf]);
            }
        }
        __syncthreads();
#pragma unroll
        for (int q = 0; q < 16; q++) {
            const int s = t + q * 512;
            const int row = s >> 5, c8 = s & 31;
            const int gcol = n0 + c8 * 8;
            if (gcol < Nvalid)
                *(us8*)&C[(size_t)(m0 + row) * Npitch + gcol] =
                    *(const us8*)(Smb + row * 512 + ((c8 * 16) ^ (((row >> 2) & 3) << 5)));
        }
    } else {
        float* Ct = (float*)Cv;
        float* Cf = (float*)Sm;   // 128 rows x 256 f32 = 128 KiB per pass
#pragma unroll
        for (int p = 0; p < 2; p++) {
            __syncthreads();
            if (wm == p) {
#pragma unroll
                for (int mf = 0; mf < 8; mf++)
#pragma unroll
                    for (int nf = 0; nf < 4; nf++) {
                        // window-XOR: phys window = (wn*4+nf)^qd -> 2-way banks
                        const int pcol = wn * 64 + ((nf ^ qd) * 16) + ln;
#pragma unroll
                        for (int r = 0; r < 4; r++)
                            Cf[(mf * 16 + qd * 4 + r) * 256 + pcol] = acc[mf][nf][r] + bv[nf];
                    }
            }
            __syncthreads();
#pragma unroll
            for (int q = 0; q < 16; q++) {
                const int c = t + q * 512;
                const int row = c >> 6, cc = c & 63;   // 64 f32x4 chunks/row
                const int gcol = n0 + cc * 4;
                if (gcol < Nvalid)
                    *(f32x4*)&Ct[(size_t)(m0 + p * 128 + row) * Npitch + gcol] =
                        *(const f32x4*)&Cf[row * 256 + ((cc ^ (((row >> 2) & 3) << 2)) * 4)];
            }
        }
    }
}

// ---------------------------------------------------------------------------
// RoPE.  Q: in-place in qkv[s][0..1151], PRE-SCALED by 72^-0.5 * log2(e)
// (softmax scale folded here; flash_attn then uses raw exp2).
// K: -> k_buf [128 nh][1024 l][128] (cols 72..127 zero).
// ---------------------------------------------------------------------------
__global__ void rope_qk(ushort_t* __restrict__ qkv,
                        const float* __restrict__ cosb,
                        const float* __restrict__ sinb,
                        ushort_t* __restrict__ kb)
{
    const int idx = blockIdx.x * 256 + threadIdx.x;   // < 8192*144
    const int d0c = idx % 9;
    const int h = (idx / 9) & 15;
    const int s = idx / 144;
    const int d0 = d0c * 4;
    const int n = s >> 10, l = s & 1023;
    const size_t src = (size_t)s * 3456 + h * 72;
    const size_t dstrow = ((size_t)(n * 16 + h) * 1024 + l) * 128;
    const float SQ = 0.17002325f;   // 72^-0.5 * log2(e)

    f32x4 c1 = *(const f32x4*)&cosb[s * 72 + d0];
    f32x4 c2 = *(const f32x4*)&cosb[s * 72 + d0 + 36];
    f32x4 s1 = *(const f32x4*)&sinb[s * 72 + d0];
    f32x4 s2 = *(const f32x4*)&sinb[s * 72 + d0 + 36];

    {   // Q (in place, pre-scaled)
        us4 x1 = *(const us4*)&qkv[src + d0];
        us4 x2 = *(const us4*)&qkv[src + d0 + 36];
        us4 o1, o2;
#pragma unroll
        for (int j = 0; j < 4; j++) {
            float a = b2f(x1[j]), b = b2f(x2[j]);
            o1[j] = f2b((a * c1[j] - b * s1[j]) * SQ);
            o2[j] = f2b((b * c2[j] + a * s2[j]) * SQ);
        }
        *(us4*)&qkv[src + d0] = o1;
        *(us4*)&qkv[src + d0 + 36] = o2;
    }
    {   // K -> padded k_buf
        us4 x1 = *(const us4*)&qkv[src + 1152 + d0];
        us4 x2 = *(const us4*)&qkv[src + 1152 + d0 + 36];
        us4 o1, o2;
#pragma unroll
        for (int j = 0; j < 4; j++) {
            float a = b2f(x1[j]), b = b2f(x2[j]);
            o1[j] = f2b(a * c1[j] - b * s1[j]);
            o2[j] = f2b(b * c2[j] + a * s2[j]);
        }
        *(us4*)&kb[dstrow + d0] = o1;
        *(us4*)&kb[dstrow + d0 + 36] = o2;
    }
    if (d0c < 7) {   // zero pad cols 72..127 (7 x us8)
        us8 z = (us8){0, 0, 0, 0, 0, 0, 0, 0};
        *(us8*)&kb[dstrow + 72 + d0c * 8] = z;
    }
}

// ---------------------------------------------------------------------------
// V transpose: qkv(bf16)[s][2304+h*72+d] -> Vt [128 nh][80 d][1024 kv]
// (rows d=72..79 zero).  kv order within each 32-kv subtile INTERLEAVED:
// phys slot s holds logical k = (s>>1) + (s&1)*16 (matches packed P-store).
// ---------------------------------------------------------------------------
__global__ void v_transpose(const ushort_t* __restrict__ qkv, ushort_t* __restrict__ vt)
{
    __shared__ short T[64 * 80];
    const int t = threadIdx.x;
    const int nh = blockIdx.x >> 4, kvb = blockIdx.x & 15;
    const int h = nh & 15, n = nh >> 4;
    const int s0 = n * 1024 + kvb * 64;

#pragma unroll
    for (int i = 0; i < 3; i++) {
        int c = t + i * 256;
        if (c < 576) {
            int row = c / 9, off = (c % 9) * 8;
            *(us8*)&T[row * 80 + off] =
                *(const us8*)&qkv[(size_t)(s0 + row) * 3456 + 2304 + h * 72 + off];
        }
    }
    __syncthreads();

#pragma unroll
    for (int i = 0; i < 3; i++) {
        int c = t + i * 256;
        if (c < 640) {
            int d = c >> 3, kc = c & 7;
            us8 o;
            if (d < 72) {
#pragma unroll
                for (int j = 0; j < 8; j++) {
                    int l64 = kc * 8 + j;                 // phys slot in 64-tile
                    int b = l64 >> 5, s = l64 & 31;
                    int kl = (s >> 1) + ((s & 1) << 4);   // logical k in 32-subtile
                    o[j] = (ushort_t)T[(b * 32 + kl) * 80 + d];
                }
            } else {
                o = (us8){0, 0, 0, 0, 0, 0, 0, 0};
            }
            *(us8*)&vt[((size_t)nh * 80 + d) * 1024 + kvb * 64 + kc * 8] = o;
        }
    }
}

// ---------------------------------------------------------------------------
// Flash attention v2: block = (nh, 256-q tile), 4 waves x 64 q-rows each.
// BKV=32.  Static softmax (Q pre-scaled -> exp2), per-lane partial row-sums,
// epilogue reduction.  K/V double-buffered swizzled DMA; Ps pitch 40.
// P-store: interleaved kv pairs packed via explicit RNE + v_perm_b32
// (lo=bf16(p0), hi=bf16(p1)); short-typed store (TBAA) + compiler fence.
// ---------------------------------------------------------------------------
__global__ __launch_bounds__(256, 2) void flash_attn(
    const ushort_t* __restrict__ qkv, const ushort_t* __restrict__ kb,
    const ushort_t* __restrict__ vt, ushort_t* __restrict__ ob)
{
    __shared__ short Ks[2][32 * 128];   // 16384 B  row pitch 256 B
    __shared__ short VtS[2][80 * 32];   // 10240 B  row pitch 64 B
    __shared__ short Ps[4][64 * 40];    // 20480 B  -> total 47104 B

    const int t = threadIdx.x;
    const int lane = t & 63, w = t >> 6;
    const int qd = lane >> 4, ln = lane & 15;
    const int lnx = ln & 7;
    const int lns = (ln >> 1) & 3;
    const int nh = blockIdx.x >> 2, qt = blockIdx.x & 3;
    const int q0 = qt * 256;
    const int h = nh & 15, n = nh >> 4;

    const ushort_t* kbase = kb + (size_t)nh * 1024 * 128;
    const ushort_t* vbase = vt + (size_t)nh * 80 * 1024;

    // ---- Q fragments -> registers.  Wave w owns q rows q0+w*64 .. +63 ----
    bf16x8 qf[4][3];
    {
        const ushort_t* qsrc = qkv + (size_t)(n * 1024 + q0 + w * 64) * 3456 + h * 72;
#pragma unroll
        for (int im = 0; im < 4; im++)
#pragma unroll
            for (int ks = 0; ks < 3; ks++)
                qf[im][ks] = *(const bf16x8*)&qsrc[(size_t)(im * 16 + ln) * 3456 + ks * 32 + qd * 8];
    }

    // ---- prologue: swizzled DMA of kv-tile 0 into buffer 0 ----
#pragma unroll
    for (int i = 0; i < 2; i++) {      // K: 512 chunks (32 rows x 16)
        int c = t + i * 256, r = c >> 4, kc = c & 15;
        gload_lds16(kbase + (size_t)r * 128 + (kc ^ (r & 7)) * 8, &Ks[0][c * 8]);
    }
    {                                   // V: 320 chunks (80 rows x 4)
        int c = t, d = c >> 2, kc = c & 3;
        gload_lds16(vbase + (size_t)d * 1024 + (kc ^ ((d >> 1) & 3)) * 8, &VtS[0][c * 8]);
        if (t < 64) {
            int c2 = t + 256, d2 = c2 >> 2, kc2 = c2 & 3;
            gload_lds16(vbase + (size_t)d2 * 1024 + (kc2 ^ ((d2 >> 1) & 3)) * 8, &VtS[0][c2 * 8]);
        }
    }

    float l_lane[4][4];
    f32x4 acc_o[4][5];
#pragma unroll
    for (int im = 0; im < 4; im++) {
#pragma unroll
        for (int r = 0; r < 4; r++) l_lane[im][r] = 0.f;
#pragma unroll
        for (int jn = 0; jn < 5; jn++) acc_o[im][jn] = (f32x4){0.f, 0.f, 0.f, 0.f};
    }

    for (int it = 0; it < 32; it++) {
        __syncthreads();   // drains DMAs issued last iter; buf^1 free

        if (it < 31) {     // swizzled DMA for kv-tile it+1
            const int nb = (it + 1) & 1;
            const ushort_t* knext = kbase + (size_t)(it + 1) * 4096;
#pragma unroll
            for (int i = 0; i < 2; i++) {
                int c = t + i * 256, r = c >> 4, kc = c & 15;
                gload_lds16(knext + (size_t)r * 128 + (kc ^ (r & 7)) * 8, &Ks[nb][c * 8]);
            }
            const ushort_t* vnext = vbase + (it + 1) * 32;
            {
                int c = t, d = c >> 2, kc = c & 3;
                gload_lds16(vnext + (size_t)d * 1024 + (kc ^ ((d >> 1) & 3)) * 8, &VtS[nb][c * 8]);
                if (t < 64) {
                    int c2 = t + 256, d2 = c2 >> 2, kc2 = c2 & 3;
                    gload_lds16(vnext + (size_t)d2 * 1024 + (kc2 ^ ((d2 >> 1) & 3)) * 8, &VtS[nb][c2 * 8]);
                }
            }
        }

        const short* KsB = Ks[it & 1];
        const short* VtB = VtS[it & 1];

        // ---- Q K^T ----  24 MFMA (4 im x 2 jk x 3 ks)
        f32x4 sc[4][2];
#pragma unroll
        for (int im = 0; im < 4; im++)
#pragma unroll
            for (int jk = 0; jk < 2; jk++) sc[im][jk] = (f32x4){0.f, 0.f, 0.f, 0.f};
#pragma unroll
        for (int ks = 0; ks < 3; ks++) {
            const int m = ks * 4 + qd;
#pragma unroll
            for (int jk = 0; jk < 2; jk++) {
                bf16x8 bfr = *(const bf16x8*)&KsB[(jk * 16 + ln) * 128 + (m ^ lnx) * 8];
#pragma unroll
                for (int im = 0; im < 4; im++)
                    sc[im][jk] = __builtin_amdgcn_mfma_f32_16x16x32_bf16(
                        qf[im][ks], bfr, sc[im][jk], 0, 0, 0);
            }
        }

        // ---- static softmax: p = exp2(sc); explicit RNE pair pack ----
#pragma unroll
        for (int im = 0; im < 4; im++) {
#pragma unroll
            for (int r = 0; r < 4; r++) {
                float p0 = EXP2F(sc[im][0][r]);
                float p1 = EXP2F(sc[im][1][r]);
                l_lane[im][r] += p0 + p1;
                union { float f; unsigned int i; } u0, u1;
                u0.f = p0; u1.f = p1;
                unsigned int r0 = u0.i + 0x7fffu + ((u0.i >> 16) & 1u);
                unsigned int r1 = u1.i + 0x7fffu + ((u1.i >> 16) & 1u);
                // lo16 = r0>>16 = bf16(p0), hi16 = r1>>16 = bf16(p1)
                unsigned int pk = __builtin_amdgcn_perm(r1, r0, 0x07060302u);
                union { unsigned int u; s16x2 v; } cv; cv.u = pk;
                *(s16x2*)((char*)&Ps[w][0] + (im * 16 + qd * 4 + r) * 80 + ln * 4) = cv.v;
            }
        }
        asm volatile("" ::: "memory");   // pin P-stores before PV ds_reads

        // ---- P V ----  20 MFMA (4 im x 5 jn), single K=32 pass
#pragma unroll
        for (int jn = 0; jn < 5; jn++) {
            bf16x8 vf = *(const bf16x8*)&VtB[(jn * 16 + ln) * 32 + (qd ^ lns) * 8];
#pragma unroll
            for (int im = 0; im < 4; im++) {
                bf16x8 pf = *(const bf16x8*)&Ps[w][(im * 16 + ln) * 40 + qd * 8];
                acc_o[im][jn] = __builtin_amdgcn_mfma_f32_16x16x32_bf16(
                    pf, vf, acc_o[im][jn], 0, 0, 0);
            }
        }
    }

    // ---- epilogue: reduce l across the 16-lane group, normalize, store ----
    const size_t obase = ((size_t)(n * 1024 + q0 + w * 64)) * 1152 + h * 72;
#pragma unroll
    for (int im = 0; im < 4; im++) {
#pragma unroll
        for (int r = 0; r < 4; r++) {
            float l = l_lane[im][r];
            l += __shfl_xor(l, 1);
            l += __shfl_xor(l, 2);
            l += __shfl_xor(l, 4);
            l += __shfl_xor(l, 8);
            const float inv = 1.0f / l;
            const int rowl = im * 16 + qd * 4 + r;
#pragma unroll
            for (int jn = 0; jn < 5; jn++) {
                const int d = jn * 16 + ln;
                if (d < 72)
                    ob[obase + (size_t)rowl * 1152 + d] = f2b(acc_o[im][jn][r] * inv);
            }
        }
    }
}

// ---------------------------------------------------------------------------
extern "C" void kernel_launch(void* const* d_in, const int* in_sizes, int n_in,
                              void* d_out, int out_size, void* d_ws, size_t ws_size,
                              hipStream_t stream)
{
    const float* hs     = (const float*)d_in[0];
    const float* cosb   = (const float*)d_in[1];
    const float* sinb   = (const float*)d_in[2];
    const float* qkv_w  = (const float*)d_in[3];
    const float* qkv_b  = (const float*)d_in[4];
    const float* proj_w = (const float*)d_in[5];
    const float* proj_b = (const float*)d_in[6];

    char* ws = (char*)d_ws;
    // hidden_bf16 (dead after gemm1) aliases attn (written by flash_attn)
    ushort_t* hs_bf   = (ushort_t*)(ws);                //  8192*1152*2 = 18,874,368
    ushort_t* attn    = (ushort_t*)(ws);                //  aliases hs_bf
    ushort_t* qkvw_bf = (ushort_t*)(ws + 18874368);     //  3456*1152*2 =  7,962,624
    ushort_t* projw_bf= (ushort_t*)(ws + 26836992);     //  1152*1152*2 =  2,654,208
    ushort_t* qkv_tmp = (ushort_t*)(ws + 29491200);     //  8192*3456*2 = 56,623,104
    ushort_t* k_buf   = (ushort_t*)(ws + 86114304);     //  128*1024*128*2 = 33,554,432
    ushort_t* v_t     = (ushort_t*)(ws + 119668736);    //  128*80*1024*2  = 20,971,520
    float*    out     = (float*)d_out;                  //  total ws: 140,640,256 B

    // fused fp32->bf16 converts: 1179648 + 497664 + 165888 = 1843200 = 7200*256
    cvt3_f32_bf16<<<7200, 256, 0, stream>>>(hs, hs_bf, 1179648,
                                            qkv_w, qkvw_bf, 497664,
                                            proj_w, projw_bf, 165888);

    // QKV GEMM: M=8192, N=3456 (14 x 256 tiles, last masked), K=1152
    gemm256_bt_bias<false><<<dim3(14, 32), 512, 0, stream>>>(hs_bf, qkvw_bf, qkv_b, qkv_tmp, 1152, 3456, 3456);
    rope_qk<<<4608, 256, 0, stream>>>(qkv_tmp, cosb, sinb, k_buf);
    v_transpose<<<2048, 256, 0, stream>>>(qkv_tmp, v_t);
    flash_attn<<<512, 256, 0, stream>>>(qkv_tmp, k_buf, v_t, attn);
    // proj GEMM on the 256-tile structure: M=8192, N=1152 (5 tiles, last
    // masked; B-overread lands in mapped qkv_tmp), K=1152, f32 out.
    gemm256_bt_bias<true><<<dim3(5, 32), 512, 0, stream>>>(attn, projw_bf, proj_b, out, 1152, 1152, 1152);
}

// Round 12
// 319.707 us; speedup vs baseline: 1.0160x; 1.0160x over previous
//
#include <hip/hip_runtime.h>
#include <stdint.h>

typedef unsigned short ushort_t;
typedef short bf16x8 __attribute__((ext_vector_type(8)));
typedef short s16x2 __attribute__((ext_vector_type(2)));
typedef float f32x4 __attribute__((ext_vector_type(4)));
typedef ushort_t us2 __attribute__((ext_vector_type(2)));
typedef ushort_t us4 __attribute__((ext_vector_type(4)));
typedef ushort_t us8 __attribute__((ext_vector_type(8)));

__device__ __forceinline__ float b2f(ushort_t u) {
    union { unsigned int i; float f; } v; v.i = ((unsigned int)u) << 16; return v.f;
}
__device__ __forceinline__ ushort_t f2b(float f) {
    union { float f; unsigned int i; } v; v.f = f;
    unsigned int r = v.i + 0x7fffu + ((v.i >> 16) & 1u);
    return (ushort_t)(r >> 16);
}

#if __has_builtin(__builtin_amdgcn_exp2f)
#define EXP2F(x) __builtin_amdgcn_exp2f(x)
#else
#define EXP2F(x) exp2f(x)
#endif

typedef __attribute__((address_space(3))) unsigned int lds_u32;
typedef __attribute__((address_space(1))) const unsigned int gbl_u32;

__device__ __forceinline__ void gload_lds16(const void* g, void* l) {
    __builtin_amdgcn_global_load_lds((gbl_u32*)g, (lds_u32*)l, 16, 0, 0);
}

// ---------------------------------------------------------------------------
// fp32 -> bf16 elementwise convert, 8 elems/thread, THREE buffers fused into
// one launch (hs | qkv_w | proj_w): 7200 blocks x 256 thr.
// ---------------------------------------------------------------------------
__global__ void cvt3_f32_bf16(const float* __restrict__ s0, ushort_t* __restrict__ d0, int n0,
                              const float* __restrict__ s1, ushort_t* __restrict__ d1, int n1,
                              const float* __restrict__ s2, ushort_t* __restrict__ d2, int n2)
{
    int i = blockIdx.x * 256 + threadIdx.x;
    const float* s; ushort_t* d; int j;
    if (i < n0)           { s = s0; d = d0; j = i; }
    else if (i < n0 + n1) { s = s1; d = d1; j = i - n0; }
    else if (i < n0 + n1 + n2) { s = s2; d = d2; j = i - n0 - n1; }
    else return;
    f32x4 a = *(const f32x4*)&s[(size_t)j * 8];
    f32x4 b = *(const f32x4*)&s[(size_t)j * 8 + 4];
    us8 o;
#pragma unroll
    for (int k = 0; k < 4; k++) { o[k] = f2b(a[k]); o[k + 4] = f2b(b[k]); }
    *(us8*)&d[(size_t)j * 8] = o;
}

// ---------------------------------------------------------------------------
// gemm256 v2 (FINAL -- schedule ladder: v1(2bar,16/0/8/0)=85.7,
// v2(1bar,10/6/8/0)=78-79 BEST, v3(prefetch;lgkm0 drains it)=82.4,
// v4(2phase;24/0 burst)=88.4, v5(2bar balanced;m201 shape)=84.0.
// 2 blocks/CU impossible: 256^2 acc alone = 128 regs/wave (unified file)).
// C = A @ B^T + bias.  256x256 tile, BK=64, 512 thr (8 waves 2Mx4N, per-wave
// 128x64), double-buffered 128 KiB LDS.  4 phases/K-tile, ONE barrier per
// phase, read distribution 10/6/8/0, counted vmcnt(4) at K-tile boundaries,
// setprio, XOR (r&7) swizzle via pre-swizzled global source.
// OUT_F32=false: bf16 C, swizzled LDS-staged us8 stores.
// OUT_F32=true : f32 C, two half-tile LDS passes, window-XOR (nf^qd).
// N need not divide 256: overreads land in mapped ws; stores masked.
// ---------------------------------------------------------------------------
template <bool OUT_F32>
__global__ __launch_bounds__(512, 2) void gemm256_bt_bias(
    const ushort_t* __restrict__ A, const ushort_t* __restrict__ B,
    const float* __restrict__ bias, void* __restrict__ Cv,
    int K, int Npitch, int Nvalid)
{
    __shared__ short Sm[65536];   // 128 KiB: buf{0,1} x [A 256x64 | B 256x64]

    const int t = threadIdx.x;
    const int lane = t & 63, w = t >> 6;
    const int qd = lane >> 4, ln = lane & 15;
    const int wm = w >> 2, wn = w & 3;

    // XCD-aware bijective swizzle (grid size % 8 == 0 for both uses)
    const int nwgx = gridDim.x;
    const int bid = blockIdx.y * nwgx + blockIdx.x;
    const int q8 = (nwgx * gridDim.y) >> 3;
    const int swz = (bid & 7) * q8 + (bid >> 3);
    const int m0 = (swz / nwgx) * 256, n0 = (swz % nwgx) * 256;

    const int NT = K >> 6;   // number of 64-wide K-tiles
    const int H4 = K >> 4;   // total half-tiles (4 per K-tile)

    const int sr = t >> 3, sc = t & 7;
    const int csw = (sc ^ (sr & 7)) * 8;
    const ushort_t* pA = A + (size_t)(m0 + sr) * K + csw;
    const ushort_t* pB = B + (size_t)(n0 + sr) * K + csw;
    const size_t rowK64 = (size_t)64 * K;
    const size_t rowK128 = (size_t)128 * K;

    auto stage = [&](int h) {
        if (h >= H4) return;
        const int ktt = h >> 2, reg = h & 3;
        const ushort_t* s0;
        int lo;
        if (reg == 0)      { s0 = pB;           lo = 16384; }
        else if (reg == 1) { s0 = pB + rowK128; lo = 24576; }
        else if (reg == 2) { s0 = pA;           lo = 0;     }
        else               { s0 = pA + rowK128; lo = 8192;  }
        short* d = &Sm[(ktt & 1) * 32768 + lo + t * 8];
        const ushort_t* g = s0 + (size_t)ktt * 64;
        gload_lds16(g, d);                       // rows 0..63 of half-tile
        gload_lds16(g + rowK64, d + 4096);       // rows 64..127
    };

    f32x4 acc[8][4];
#pragma unroll
    for (int i = 0; i < 8; i++)
#pragma unroll
        for (int j = 0; j < 4; j++) acc[i][j] = (f32x4){0.f, 0.f, 0.f, 0.f};

    const int pc0 = (qd ^ (ln & 7)) * 8;
    const int pc1 = ((4 + qd) ^ (ln & 7)) * 8;
    const int arow = wm * 128 + ln;
    const int brow = wn * 64 + ln;

    // ---- prologue: half-tiles 0..5 (kt0 complete + B0,B1 of kt1) ----
#pragma unroll
    for (int h = 0; h < 6; h++) stage(h);
    asm volatile("s_waitcnt vmcnt(4)" ::: "memory");
    __builtin_amdgcn_s_barrier();

    for (int kt = 0; kt < NT; kt++) {
        const int buf = (kt & 1) * 32768;
        const short* Ab = &Sm[buf];
        const short* Bb = &Sm[buf + 16384];
        const int p = kt * 4;

        bf16x8 a[8], bk0[4], bk1[4];

        // -------- phase 0: reads a0[8]+bk0[0,1]; stage A0(kt+1); MFMA x16
#pragma unroll
        for (int mf = 0; mf < 8; mf++)
            a[mf] = *(const bf16x8*)&Ab[(arow + mf * 16) * 64 + pc0];
        bk0[0] = *(const bf16x8*)&Bb[(brow + 0)  * 64 + pc0];
        bk0[1] = *(const bf16x8*)&Bb[(brow + 16) * 64 + pc0];
        stage(p + 6);
        __builtin_amdgcn_s_setprio(1);
#pragma unroll
        for (int mf = 0; mf < 8; mf++) {
            acc[mf][0] = __builtin_amdgcn_mfma_f32_16x16x32_bf16(a[mf], bk0[0], acc[mf][0], 0, 0, 0);
            acc[mf][1] = __builtin_amdgcn_mfma_f32_16x16x32_bf16(a[mf], bk0[1], acc[mf][1], 0, 0, 0);
        }
        __builtin_amdgcn_s_setprio(0);
        asm volatile("s_waitcnt lgkmcnt(0)" ::: "memory");
        __builtin_amdgcn_s_barrier();

        // -------- phase 1: reads bk0[2,3]+bk1[0..3]; stage A1(kt+1); MFMA x16
        bk0[2] = *(const bf16x8*)&Bb[(brow + 32) * 64 + pc0];
        bk0[3] = *(const bf16x8*)&Bb[(brow + 48) * 64 + pc0];
#pragma unroll
        for (int nf = 0; nf < 4; nf++)
            bk1[nf] = *(const bf16x8*)&Bb[(brow + nf * 16) * 64 + pc1];
        stage(p + 7);
        __builtin_amdgcn_s_setprio(1);
#pragma unroll
        for (int mf = 0; mf < 8; mf++) {
            acc[mf][2] = __builtin_amdgcn_mfma_f32_16x16x32_bf16(a[mf], bk0[2], acc[mf][2], 0, 0, 0);
            acc[mf][3] = __builtin_amdgcn_mfma_f32_16x16x32_bf16(a[mf], bk0[3], acc[mf][3], 0, 0, 0);
        }
        __builtin_amdgcn_s_setprio(0);
        asm volatile("s_waitcnt lgkmcnt(0)" ::: "memory");
        __builtin_amdgcn_s_barrier();

        // -------- phase 2: reads a1[8]; stage B0(kt+2); MFMA x16
#pragma unroll
        for (int mf = 0; mf < 8; mf++)
            a[mf] = *(const bf16x8*)&Ab[(arow + mf * 16) * 64 + pc1];
        stage(p + 8);
        __builtin_amdgcn_s_setprio(1);
#pragma unroll
        for (int mf = 0; mf < 8; mf++) {
            acc[mf][0] = __builtin_amdgcn_mfma_f32_16x16x32_bf16(a[mf], bk1[0], acc[mf][0], 0, 0, 0);
            acc[mf][1] = __builtin_amdgcn_mfma_f32_16x16x32_bf16(a[mf], bk1[1], acc[mf][1], 0, 0, 0);
        }
        __builtin_amdgcn_s_setprio(0);
        asm volatile("s_waitcnt lgkmcnt(0)" ::: "memory");
        __builtin_amdgcn_s_barrier();

        // -------- phase 3: stage B1(kt+2); MFMA x16; counted vmcnt boundary
        stage(p + 9);
        __builtin_amdgcn_s_setprio(1);
#pragma unroll
        for (int mf = 0; mf < 8; mf++) {
            acc[mf][2] = __builtin_amdgcn_mfma_f32_16x16x32_bf16(a[mf], bk1[2], acc[mf][2], 0, 0, 0);
            acc[mf][3] = __builtin_amdgcn_mfma_f32_16x16x32_bf16(a[mf], bk1[3], acc[mf][3], 0, 0, 0);
        }
        __builtin_amdgcn_s_setprio(0);
        asm volatile("s_waitcnt lgkmcnt(0)" ::: "memory");
        if (kt < NT - 2) { asm volatile("s_waitcnt vmcnt(4)" ::: "memory"); }
        else             { asm volatile("s_waitcnt vmcnt(0)" ::: "memory"); }
        __builtin_amdgcn_s_barrier();
    }

    // ---- epilogue ----
    __syncthreads();
    float bv[4];
#pragma unroll
    for (int nf = 0; nf < 4; nf++) {
        const int gc = n0 + wn * 64 + nf * 16 + ln;
        bv[nf] = (gc < Nvalid) ? bias[gc] : 0.f;
    }

    if (!OUT_F32) {
        ushort_t* C = (ushort_t*)Cv;
        char* Smb = (char*)Sm;
#pragma unroll
        for (int mf = 0; mf < 8; mf++) {
            const int row = wm * 128 + mf * 16 + qd * 4;
#pragma unroll
            for (int nf = 0; nf < 4; nf++) {
                const int swc = ((wn * 64 + nf * 16 + ln) * 2) ^ (qd << 5);
#pragma unroll
                for (int r = 0; r < 4; r++)
                    *(ushort_t*)(Smb + (row + r) * 512 + swc) = f2b(acc[mf][nf][r] + bv[nf]);
            }
        }
        __syncthreads();
#pragma unroll
        for (int q = 0; q < 16; q++) {
            const int s = t + q * 512;
            const int row = s >> 5, c8 = s & 31;
            const int gcol = n0 + c8 * 8;
            if (gcol < Nvalid)
                *(us8*)&C[(size_t)(m0 + row) * Npitch + gcol] =
                    *(const us8*)(Smb + row * 512 + ((c8 * 16) ^ (((row >> 2) & 3) << 5)));
        }
    } else {
        float* Ct = (float*)Cv;
        float* Cf = (float*)Sm;   // 128 rows x 256 f32 = 128 KiB per pass
#pragma unroll
        for (int p = 0; p < 2; p++) {
            __syncthreads();
            if (wm == p) {
#pragma unroll
                for (int mf = 0; mf < 8; mf++)
#pragma unroll
                    for (int nf = 0; nf < 4; nf++) {
                        // window-XOR: phys window = (wn*4+nf)^qd -> 2-way banks
                        const int pcol = wn * 64 + ((nf ^ qd) * 16) + ln;
#pragma unroll
                        for (int r = 0; r < 4; r++)
                            Cf[(mf * 16 + qd * 4 + r) * 256 + pcol] = acc[mf][nf][r] + bv[nf];
                    }
            }
            __syncthreads();
#pragma unroll
            for (int q = 0; q < 16; q++) {
                const int c = t + q * 512;
                const int row = c >> 6, cc = c & 63;   // 64 f32x4 chunks/row
                const int gcol = n0 + cc * 4;
                if (gcol < Nvalid)
                    *(f32x4*)&Ct[(size_t)(m0 + p * 128 + row) * Npitch + gcol] =
                        *(const f32x4*)&Cf[row * 256 + ((cc ^ (((row >> 2) & 3) << 2)) * 4)];
            }
        }
    }
}

// ---------------------------------------------------------------------------
// RoPE.  Q: in-place in qkv[s][0..1151], PRE-SCALED by 72^-0.5 * log2(e)
// (softmax scale folded here; flash_attn then uses raw exp2).
// K: -> k_buf [128 nh][1024 l][128] (cols 72..127 zero).
// ---------------------------------------------------------------------------
__global__ void rope_qk(ushort_t* __restrict__ qkv,
                        const float* __restrict__ cosb,
                        const float* __restrict__ sinb,
                        ushort_t* __restrict__ kb)
{
    const int idx = blockIdx.x * 256 + threadIdx.x;   // < 8192*144
    const int d0c = idx % 9;
    const int h = (idx / 9) & 15;
    const int s = idx / 144;
    const int d0 = d0c * 4;
    const int n = s >> 10, l = s & 1023;
    const size_t src = (size_t)s * 3456 + h * 72;
    const size_t dstrow = ((size_t)(n * 16 + h) * 1024 + l) * 128;
    const float SQ = 0.17002325f;   // 72^-0.5 * log2(e)

    f32x4 c1 = *(const f32x4*)&cosb[s * 72 + d0];
    f32x4 c2 = *(const f32x4*)&cosb[s * 72 + d0 + 36];
    f32x4 s1 = *(const f32x4*)&sinb[s * 72 + d0];
    f32x4 s2 = *(const f32x4*)&sinb[s * 72 + d0 + 36];

    {   // Q (in place, pre-scaled)
        us4 x1 = *(const us4*)&qkv[src + d0];
        us4 x2 = *(const us4*)&qkv[src + d0 + 36];
        us4 o1, o2;
#pragma unroll
        for (int j = 0; j < 4; j++) {
            float a = b2f(x1[j]), b = b2f(x2[j]);
            o1[j] = f2b((a * c1[j] - b * s1[j]) * SQ);
            o2[j] = f2b((b * c2[j] + a * s2[j]) * SQ);
        }
        *(us4*)&qkv[src + d0] = o1;
        *(us4*)&qkv[src + d0 + 36] = o2;
    }
    {   // K -> padded k_buf
        us4 x1 = *(const us4*)&qkv[src + 1152 + d0];
        us4 x2 = *(const us4*)&qkv[src + 1152 + d0 + 36];
        us4 o1, o2;
#pragma unroll
        for (int j = 0; j < 4; j++) {
            float a = b2f(x1[j]), b = b2f(x2[j]);
            o1[j] = f2b(a * c1[j] - b * s1[j]);
            o2[j] = f2b(b * c2[j] + a * s2[j]);
        }
        *(us4*)&kb[dstrow + d0] = o1;
        *(us4*)&kb[dstrow + d0 + 36] = o2;
    }
    if (d0c < 7) {   // zero pad cols 72..127 (7 x us8)
        us8 z = (us8){0, 0, 0, 0, 0, 0, 0, 0};
        *(us8*)&kb[dstrow + 72 + d0c * 8] = z;
    }
}

// ---------------------------------------------------------------------------
// V transpose: qkv(bf16)[s][2304+h*72+d] -> Vt [128 nh][80 d][1024 kv]
// (rows d=72..79 zero).  kv order within each 32-kv subtile INTERLEAVED:
// phys slot s holds logical k = (s>>1) + (s&1)*16 (matches packed P-store).
// ---------------------------------------------------------------------------
__global__ void v_transpose(const ushort_t* __restrict__ qkv, ushort_t* __restrict__ vt)
{
    __shared__ short T[64 * 80];
    const int t = threadIdx.x;
    const int nh = blockIdx.x >> 4, kvb = blockIdx.x & 15;
    const int h = nh & 15, n = nh >> 4;
    const int s0 = n * 1024 + kvb * 64;

#pragma unroll
    for (int i = 0; i < 3; i++) {
        int c = t + i * 256;
        if (c < 576) {
            int row = c / 9, off = (c % 9) * 8;
            *(us8*)&T[row * 80 + off] =
                *(const us8*)&qkv[(size_t)(s0 + row) * 3456 + 2304 + h * 72 + off];
        }
    }
    __syncthreads();

#pragma unroll
    for (int i = 0; i < 3; i++) {
        int c = t + i * 256;
        if (c < 640) {
            int d = c >> 3, kc = c & 7;
            us8 o;
            if (d < 72) {
#pragma unroll
                for (int j = 0; j < 8; j++) {
                    int l64 = kc * 8 + j;                 // phys slot in 64-tile
                    int b = l64 >> 5, s = l64 & 31;
                    int kl = (s >> 1) + ((s & 1) << 4);   // logical k in 32-subtile
                    o[j] = (ushort_t)T[(b * 32 + kl) * 80 + d];
                }
            } else {
                o = (us8){0, 0, 0, 0, 0, 0, 0, 0};
            }
            *(us8*)&vt[((size_t)nh * 80 + d) * 1024 + kvb * 64 + kc * 8] = o;
        }
    }
}

// ---------------------------------------------------------------------------
// Flash attention v2: block = (nh, 256-q tile), 4 waves x 64 q-rows each.
// BKV=32.  Static softmax (Q pre-scaled -> exp2), per-lane partial row-sums,
// epilogue reduction.  K/V double-buffered swizzled DMA; Ps pitch 40.
// P-store: interleaved kv pairs packed via explicit RNE + v_perm_b32
// (lo=bf16(p0), hi=bf16(p1)); short-typed store (TBAA) + compiler fence.
// ---------------------------------------------------------------------------
__global__ __launch_bounds__(256, 2) void flash_attn(
    const ushort_t* __restrict__ qkv, const ushort_t* __restrict__ kb,
    const ushort_t* __restrict__ vt, ushort_t* __restrict__ ob)
{
    __shared__ short Ks[2][32 * 128];   // 16384 B  row pitch 256 B
    __shared__ short VtS[2][80 * 32];   // 10240 B  row pitch 64 B
    __shared__ short Ps[4][64 * 40];    // 20480 B  -> total 47104 B

    const int t = threadIdx.x;
    const int lane = t & 63, w = t >> 6;
    const int qd = lane >> 4, ln = lane & 15;
    const int lnx = ln & 7;
    const int lns = (ln >> 1) & 3;
    const int nh = blockIdx.x >> 2, qt = blockIdx.x & 3;
    const int q0 = qt * 256;
    const int h = nh & 15, n = nh >> 4;

    const ushort_t* kbase = kb + (size_t)nh * 1024 * 128;
    const ushort_t* vbase = vt + (size_t)nh * 80 * 1024;

    // ---- Q fragments -> registers.  Wave w owns q rows q0+w*64 .. +63 ----
    bf16x8 qf[4][3];
    {
        const ushort_t* qsrc = qkv + (size_t)(n * 1024 + q0 + w * 64) * 3456 + h * 72;
#pragma unroll
        for (int im = 0; im < 4; im++)
#pragma unroll
            for (int ks = 0; ks < 3; ks++)
                qf[im][ks] = *(const bf16x8*)&qsrc[(size_t)(im * 16 + ln) * 3456 + ks * 32 + qd * 8];
    }

    // ---- prologue: swizzled DMA of kv-tile 0 into buffer 0 ----
#pragma unroll
    for (int i = 0; i < 2; i++) {      // K: 512 chunks (32 rows x 16)
        int c = t + i * 256, r = c >> 4, kc = c & 15;
        gload_lds16(kbase + (size_t)r * 128 + (kc ^ (r & 7)) * 8, &Ks[0][c * 8]);
    }
    {                                   // V: 320 chunks (80 rows x 4)
        int c = t, d = c >> 2, kc = c & 3;
        gload_lds16(vbase + (size_t)d * 1024 + (kc ^ ((d >> 1) & 3)) * 8, &VtS[0][c * 8]);
        if (t < 64) {
            int c2 = t + 256, d2 = c2 >> 2, kc2 = c2 & 3;
            gload_lds16(vbase + (size_t)d2 * 1024 + (kc2 ^ ((d2 >> 1) & 3)) * 8, &VtS[0][c2 * 8]);
        }
    }

    float l_lane[4][4];
    f32x4 acc_o[4][5];
#pragma unroll
    for (int im = 0; im < 4; im++) {
#pragma unroll
        for (int r = 0; r < 4; r++) l_lane[im][r] = 0.f;
#pragma unroll
        for (int jn = 0; jn < 5; jn++) acc_o[im][jn] = (f32x4){0.f, 0.f, 0.f, 0.f};
    }

    for (int it = 0; it < 32; it++) {
        __syncthreads();   // drains DMAs issued last iter; buf^1 free

        if (it < 31) {     // swizzled DMA for kv-tile it+1
            const int nb = (it + 1) & 1;
            const ushort_t* knext = kbase + (size_t)(it + 1) * 4096;
#pragma unroll
            for (int i = 0; i < 2; i++) {
                int c = t + i * 256, r = c >> 4, kc = c & 15;
                gload_lds16(knext + (size_t)r * 128 + (kc ^ (r & 7)) * 8, &Ks[nb][c * 8]);
            }
            const ushort_t* vnext = vbase + (it + 1) * 32;
            {
                int c = t, d = c >> 2, kc = c & 3;
                gload_lds16(vnext + (size_t)d * 1024 + (kc ^ ((d >> 1) & 3)) * 8, &VtS[nb][c * 8]);
                if (t < 64) {
                    int c2 = t + 256, d2 = c2 >> 2, kc2 = c2 & 3;
                    gload_lds16(vnext + (size_t)d2 * 1024 + (kc2 ^ ((d2 >> 1) & 3)) * 8, &VtS[nb][c2 * 8]);
                }
            }
        }

        const short* KsB = Ks[it & 1];
        const short* VtB = VtS[it & 1];

        // ---- Q K^T ----  24 MFMA (4 im x 2 jk x 3 ks)
        f32x4 sc[4][2];
#pragma unroll
        for (int im = 0; im < 4; im++)
#pragma unroll
            for (int jk = 0; jk < 2; jk++) sc[im][jk] = (f32x4){0.f, 0.f, 0.f, 0.f};
#pragma unroll
        for (int ks = 0; ks < 3; ks++) {
            const int m = ks * 4 + qd;
#pragma unroll
            for (int jk = 0; jk < 2; jk++) {
                bf16x8 bfr = *(const bf16x8*)&KsB[(jk * 16 + ln) * 128 + (m ^ lnx) * 8];
#pragma unroll
                for (int im = 0; im < 4; im++)
                    sc[im][jk] = __builtin_amdgcn_mfma_f32_16x16x32_bf16(
                        qf[im][ks], bfr, sc[im][jk], 0, 0, 0);
            }
        }

        // ---- static softmax: p = exp2(sc); explicit RNE pair pack ----
#pragma unroll
        for (int im = 0; im < 4; im++) {
#pragma unroll
            for (int r = 0; r < 4; r++) {
                float p0 = EXP2F(sc[im][0][r]);
                float p1 = EXP2F(sc[im][1][r]);
                l_lane[im][r] += p0 + p1;
                union { float f; unsigned int i; } u0, u1;
                u0.f = p0; u1.f = p1;
                unsigned int r0 = u0.i + 0x7fffu + ((u0.i >> 16) & 1u);
                unsigned int r1 = u1.i + 0x7fffu + ((u1.i >> 16) & 1u);
                // lo16 = r0>>16 = bf16(p0), hi16 = r1>>16 = bf16(p1)
                unsigned int pk = __builtin_amdgcn_perm(r1, r0, 0x07060302u);
                union { unsigned int u; s16x2 v; } cv; cv.u = pk;
                *(s16x2*)((char*)&Ps[w][0] + (im * 16 + qd * 4 + r) * 80 + ln * 4) = cv.v;
            }
        }
        asm volatile("" ::: "memory");   // pin P-stores before PV ds_reads

        // ---- P V ----  20 MFMA (4 im x 5 jn), single K=32 pass
#pragma unroll
        for (int jn = 0; jn < 5; jn++) {
            bf16x8 vf = *(const bf16x8*)&VtB[(jn * 16 + ln) * 32 + (qd ^ lns) * 8];
#pragma unroll
            for (int im = 0; im < 4; im++) {
                bf16x8 pf = *(const bf16x8*)&Ps[w][(im * 16 + ln) * 40 + qd * 8];
                acc_o[im][jn] = __builtin_amdgcn_mfma_f32_16x16x32_bf16(
                    pf, vf, acc_o[im][jn], 0, 0, 0);
            }
        }
    }

    // ---- epilogue: reduce l across the 16-lane group, normalize, store ----
    const size_t obase = ((size_t)(n * 1024 + q0 + w * 64)) * 1152 + h * 72;
#pragma unroll
    for (int im = 0; im < 4; im++) {
#pragma unroll
        for (int r = 0; r < 4; r++) {
            float l = l_lane[im][r];
            l += __shfl_xor(l, 1);
            l += __shfl_xor(l, 2);
            l += __shfl_xor(l, 4);
            l += __shfl_xor(l, 8);
            const float inv = 1.0f / l;
            const int rowl = im * 16 + qd * 4 + r;
#pragma unroll
            for (int jn = 0; jn < 5; jn++) {
                const int d = jn * 16 + ln;
                if (d < 72)
                    ob[obase + (size_t)rowl * 1152 + d] = f2b(acc_o[im][jn][r] * inv);
            }
        }
    }
}

// ---------------------------------------------------------------------------
extern "C" void kernel_launch(void* const* d_in, const int* in_sizes, int n_in,
                              void* d_out, int out_size, void* d_ws, size_t ws_size,
                              hipStream_t stream)
{
    const float* hs     = (const float*)d_in[0];
    const float* cosb   = (const float*)d_in[1];
    const float* sinb   = (const float*)d_in[2];
    const float* qkv_w  = (const float*)d_in[3];
    const float* qkv_b  = (const float*)d_in[4];
    const float* proj_w = (const float*)d_in[5];
    const float* proj_b = (const float*)d_in[6];

    char* ws = (char*)d_ws;
    // hidden_bf16 (dead after gemm1) aliases attn (written by flash_attn)
    ushort_t* hs_bf   = (ushort_t*)(ws);                //  8192*1152*2 = 18,874,368
    ushort_t* attn    = (ushort_t*)(ws);                //  aliases hs_bf
    ushort_t* qkvw_bf = (ushort_t*)(ws + 18874368);     //  3456*1152*2 =  7,962,624
    ushort_t* projw_bf= (ushort_t*)(ws + 26836992);     //  1152*1152*2 =  2,654,208
    ushort_t* qkv_tmp = (ushort_t*)(ws + 29491200);     //  8192*3456*2 = 56,623,104
    ushort_t* k_buf   = (ushort_t*)(ws + 86114304);     //  128*1024*128*2 = 33,554,432
    ushort_t* v_t     = (ushort_t*)(ws + 119668736);    //  128*80*1024*2  = 20,971,520
    float*    out     = (float*)d_out;                  //  total ws: 140,640,256 B

    // fused fp32->bf16 converts: 1179648 + 497664 + 165888 = 1843200 = 7200*256
    cvt3_f32_bf16<<<7200, 256, 0, stream>>>(hs, hs_bf, 1179648,
                                            qkv_w, qkvw_bf, 497664,
                                            proj_w, projw_bf, 165888);

    // QKV GEMM: M=8192, N=3456 (14 x 256 tiles, last masked), K=1152
    gemm256_bt_bias<false><<<dim3(14, 32), 512, 0, stream>>>(hs_bf, qkvw_bf, qkv_b, qkv_tmp, 1152, 3456, 3456);
    rope_qk<<<4608, 256, 0, stream>>>(qkv_tmp, cosb, sinb, k_buf);
    v_transpose<<<2048, 256, 0, stream>>>(qkv_tmp, v_t);
    flash_attn<<<512, 256, 0, stream>>>(qkv_tmp, k_buf, v_t, attn);
    // proj GEMM on the 256-tile structure: M=8192, N=1152 (5 tiles, last
    // masked; B-overread lands in mapped qkv_tmp), K=1152, f32 out.
    gemm256_bt_bias<true><<<dim3(5, 32), 512, 0, stream>>>(attn, projw_bf, proj_b, out, 1152, 1152, 1152);
}

// Round 13
// 314.155 us; speedup vs baseline: 1.0340x; 1.0177x over previous
//
#include <hip/hip_runtime.h>
#include <stdint.h>

typedef unsigned short ushort_t;
typedef short bf16x8 __attribute__((ext_vector_type(8)));
typedef short s16x2 __attribute__((ext_vector_type(2)));
typedef float f32x4 __attribute__((ext_vector_type(4)));
typedef ushort_t us2 __attribute__((ext_vector_type(2)));
typedef ushort_t us4 __attribute__((ext_vector_type(4)));
typedef ushort_t us8 __attribute__((ext_vector_type(8)));

__device__ __forceinline__ float b2f(ushort_t u) {
    union { unsigned int i; float f; } v; v.i = ((unsigned int)u) << 16; return v.f;
}
__device__ __forceinline__ ushort_t f2b(float f) {
    union { float f; unsigned int i; } v; v.f = f;
    unsigned int r = v.i + 0x7fffu + ((v.i >> 16) & 1u);
    return (ushort_t)(r >> 16);
}

#if __has_builtin(__builtin_amdgcn_exp2f)
#define EXP2F(x) __builtin_amdgcn_exp2f(x)
#else
#define EXP2F(x) exp2f(x)
#endif

typedef __attribute__((address_space(3))) unsigned int lds_u32;
typedef __attribute__((address_space(1))) const unsigned int gbl_u32;

__device__ __forceinline__ void gload_lds16(const void* g, void* l) {
    __builtin_amdgcn_global_load_lds((gbl_u32*)g, (lds_u32*)l, 16, 0, 0);
}

// ---------------------------------------------------------------------------
// fp32 -> bf16 elementwise convert, 8 elems/thread, THREE buffers fused into
// one launch (hs | qkv_w | proj_w): 7200 blocks x 256 thr.
// ---------------------------------------------------------------------------
__global__ void cvt3_f32_bf16(const float* __restrict__ s0, ushort_t* __restrict__ d0, int n0,
                              const float* __restrict__ s1, ushort_t* __restrict__ d1, int n1,
                              const float* __restrict__ s2, ushort_t* __restrict__ d2, int n2)
{
    int i = blockIdx.x * 256 + threadIdx.x;
    const float* s; ushort_t* d; int j;
    if (i < n0)           { s = s0; d = d0; j = i; }
    else if (i < n0 + n1) { s = s1; d = d1; j = i - n0; }
    else if (i < n0 + n1 + n2) { s = s2; d = d2; j = i - n0 - n1; }
    else return;
    f32x4 a = *(const f32x4*)&s[(size_t)j * 8];
    f32x4 b = *(const f32x4*)&s[(size_t)j * 8 + 4];
    us8 o;
#pragma unroll
    for (int k = 0; k < 4; k++) { o[k] = f2b(a[k]); o[k + 4] = f2b(b[k]); }
    *(us8*)&d[(size_t)j * 8] = o;
}

// ---------------------------------------------------------------------------
// gemm256 v2 (FINAL -- schedule ladder: v1(2bar,16/0/8/0)=85.7,
// v2(1bar,10/6/8/0)=78-79 BEST, v3(prefetch;lgkm0 drains it)=82.4,
// v4(2phase;24/0 burst)=88.4, v5(2bar balanced;m201 shape)=84.0.
// 2 blocks/CU impossible: 256^2 acc alone = 128 regs/wave (unified file)).
// C = A @ B^T + bias.  256x256 tile, BK=64, 512 thr (8 waves 2Mx4N, per-wave
// 128x64), double-buffered 128 KiB LDS.  4 phases/K-tile, ONE barrier per
// phase, read distribution 10/6/8/0, counted vmcnt(4) at K-tile boundaries,
// setprio, XOR (r&7) swizzle via pre-swizzled global source.
// OUT_F32=false: bf16 C, swizzled LDS-staged us8 stores.
// OUT_F32=true : f32 C, two half-tile LDS passes, window-XOR (nf^qd).
// N need not divide 256: overreads land in mapped ws; stores masked.
// ---------------------------------------------------------------------------
template <bool OUT_F32>
__global__ __launch_bounds__(512, 2) void gemm256_bt_bias(
    const ushort_t* __restrict__ A, const ushort_t* __restrict__ B,
    const float* __restrict__ bias, void* __restrict__ Cv,
    int K, int Npitch, int Nvalid)
{
    __shared__ short Sm[65536];   // 128 KiB: buf{0,1} x [A 256x64 | B 256x64]

    const int t = threadIdx.x;
    const int lane = t & 63, w = t >> 6;
    const int qd = lane >> 4, ln = lane & 15;
    const int wm = w >> 2, wn = w & 3;

    // XCD-aware bijective swizzle (grid size % 8 == 0 for both uses)
    const int nwgx = gridDim.x;
    const int bid = blockIdx.y * nwgx + blockIdx.x;
    const int q8 = (nwgx * gridDim.y) >> 3;
    const int swz = (bid & 7) * q8 + (bid >> 3);
    const int m0 = (swz / nwgx) * 256, n0 = (swz % nwgx) * 256;

    const int NT = K >> 6;   // number of 64-wide K-tiles
    const int H4 = K >> 4;   // total half-tiles (4 per K-tile)

    const int sr = t >> 3, sc = t & 7;
    const int csw = (sc ^ (sr & 7)) * 8;
    const ushort_t* pA = A + (size_t)(m0 + sr) * K + csw;
    const ushort_t* pB = B + (size_t)(n0 + sr) * K + csw;
    const size_t rowK64 = (size_t)64 * K;
    const size_t rowK128 = (size_t)128 * K;

    auto stage = [&](int h) {
        if (h >= H4) return;
        const int ktt = h >> 2, reg = h & 3;
        const ushort_t* s0;
        int lo;
        if (reg == 0)      { s0 = pB;           lo = 16384; }
        else if (reg == 1) { s0 = pB + rowK128; lo = 24576; }
        else if (reg == 2) { s0 = pA;           lo = 0;     }
        else               { s0 = pA + rowK128; lo = 8192;  }
        short* d = &Sm[(ktt & 1) * 32768 + lo + t * 8];
        const ushort_t* g = s0 + (size_t)ktt * 64;
        gload_lds16(g, d);                       // rows 0..63 of half-tile
        gload_lds16(g + rowK64, d + 4096);       // rows 64..127
    };

    f32x4 acc[8][4];
#pragma unroll
    for (int i = 0; i < 8; i++)
#pragma unroll
        for (int j = 0; j < 4; j++) acc[i][j] = (f32x4){0.f, 0.f, 0.f, 0.f};

    const int pc0 = (qd ^ (ln & 7)) * 8;
    const int pc1 = ((4 + qd) ^ (ln & 7)) * 8;
    const int arow = wm * 128 + ln;
    const int brow = wn * 64 + ln;

    // ---- prologue: half-tiles 0..5 (kt0 complete + B0,B1 of kt1) ----
#pragma unroll
    for (int h = 0; h < 6; h++) stage(h);
    asm volatile("s_waitcnt vmcnt(4)" ::: "memory");
    __builtin_amdgcn_s_barrier();

    for (int kt = 0; kt < NT; kt++) {
        const int buf = (kt & 1) * 32768;
        const short* Ab = &Sm[buf];
        const short* Bb = &Sm[buf + 16384];
        const int p = kt * 4;

        bf16x8 a[8], bk0[4], bk1[4];

        // -------- phase 0: reads a0[8]+bk0[0,1]; stage A0(kt+1); MFMA x16
#pragma unroll
        for (int mf = 0; mf < 8; mf++)
            a[mf] = *(const bf16x8*)&Ab[(arow + mf * 16) * 64 + pc0];
        bk0[0] = *(const bf16x8*)&Bb[(brow + 0)  * 64 + pc0];
        bk0[1] = *(const bf16x8*)&Bb[(brow + 16) * 64 + pc0];
        stage(p + 6);
        __builtin_amdgcn_s_setprio(1);
#pragma unroll
        for (int mf = 0; mf < 8; mf++) {
            acc[mf][0] = __builtin_amdgcn_mfma_f32_16x16x32_bf16(a[mf], bk0[0], acc[mf][0], 0, 0, 0);
            acc[mf][1] = __builtin_amdgcn_mfma_f32_16x16x32_bf16(a[mf], bk0[1], acc[mf][1], 0, 0, 0);
        }
        __builtin_amdgcn_s_setprio(0);
        asm volatile("s_waitcnt lgkmcnt(0)" ::: "memory");
        __builtin_amdgcn_s_barrier();

        // -------- phase 1: reads bk0[2,3]+bk1[0..3]; stage A1(kt+1); MFMA x16
        bk0[2] = *(const bf16x8*)&Bb[(brow + 32) * 64 + pc0];
        bk0[3] = *(const bf16x8*)&Bb[(brow + 48) * 64 + pc0];
#pragma unroll
        for (int nf = 0; nf < 4; nf++)
            bk1[nf] = *(const bf16x8*)&Bb[(brow + nf * 16) * 64 + pc1];
        stage(p + 7);
        __builtin_amdgcn_s_setprio(1);
#pragma unroll
        for (int mf = 0; mf < 8; mf++) {
            acc[mf][2] = __builtin_amdgcn_mfma_f32_16x16x32_bf16(a[mf], bk0[2], acc[mf][2], 0, 0, 0);
            acc[mf][3] = __builtin_amdgcn_mfma_f32_16x16x32_bf16(a[mf], bk0[3], acc[mf][3], 0, 0, 0);
        }
        __builtin_amdgcn_s_setprio(0);
        asm volatile("s_waitcnt lgkmcnt(0)" ::: "memory");
        __builtin_amdgcn_s_barrier();

        // -------- phase 2: reads a1[8]; stage B0(kt+2); MFMA x16
#pragma unroll
        for (int mf = 0; mf < 8; mf++)
            a[mf] = *(const bf16x8*)&Ab[(arow + mf * 16) * 64 + pc1];
        stage(p + 8);
        __builtin_amdgcn_s_setprio(1);
#pragma unroll
        for (int mf = 0; mf < 8; mf++) {
            acc[mf][0] = __builtin_amdgcn_mfma_f32_16x16x32_bf16(a[mf], bk1[0], acc[mf][0], 0, 0, 0);
            acc[mf][1] = __builtin_amdgcn_mfma_f32_16x16x32_bf16(a[mf], bk1[1], acc[mf][1], 0, 0, 0);
        }
        __builtin_amdgcn_s_setprio(0);
        asm volatile("s_waitcnt lgkmcnt(0)" ::: "memory");
        __builtin_amdgcn_s_barrier();

        // -------- phase 3: stage B1(kt+2); MFMA x16; counted vmcnt boundary
        stage(p + 9);
        __builtin_amdgcn_s_setprio(1);
#pragma unroll
        for (int mf = 0; mf < 8; mf++) {
            acc[mf][2] = __builtin_amdgcn_mfma_f32_16x16x32_bf16(a[mf], bk1[2], acc[mf][2], 0, 0, 0);
            acc[mf][3] = __builtin_amdgcn_mfma_f32_16x16x32_bf16(a[mf], bk1[3], acc[mf][3], 0, 0, 0);
        }
        __builtin_amdgcn_s_setprio(0);
        asm volatile("s_waitcnt lgkmcnt(0)" ::: "memory");
        if (kt < NT - 2) { asm volatile("s_waitcnt vmcnt(4)" ::: "memory"); }
        else             { asm volatile("s_waitcnt vmcnt(0)" ::: "memory"); }
        __builtin_amdgcn_s_barrier();
    }

    // ---- epilogue ----
    __syncthreads();
    float bv[4];
#pragma unroll
    for (int nf = 0; nf < 4; nf++) {
        const int gc = n0 + wn * 64 + nf * 16 + ln;
        bv[nf] = (gc < Nvalid) ? bias[gc] : 0.f;
    }

    if (!OUT_F32) {
        ushort_t* C = (ushort_t*)Cv;
        char* Smb = (char*)Sm;
#pragma unroll
        for (int mf = 0; mf < 8; mf++) {
            const int row = wm * 128 + mf * 16 + qd * 4;
#pragma unroll
            for (int nf = 0; nf < 4; nf++) {
                const int swc = ((wn * 64 + nf * 16 + ln) * 2) ^ (qd << 5);
#pragma unroll
                for (int r = 0; r < 4; r++)
                    *(ushort_t*)(Smb + (row + r) * 512 + swc) = f2b(acc[mf][nf][r] + bv[nf]);
            }
        }
        __syncthreads();
#pragma unroll
        for (int q = 0; q < 16; q++) {
            const int s = t + q * 512;
            const int row = s >> 5, c8 = s & 31;
            const int gcol = n0 + c8 * 8;
            if (gcol < Nvalid)
                *(us8*)&C[(size_t)(m0 + row) * Npitch + gcol] =
                    *(const us8*)(Smb + row * 512 + ((c8 * 16) ^ (((row >> 2) & 3) << 5)));
        }
    } else {
        float* Ct = (float*)Cv;
        float* Cf = (float*)Sm;   // 128 rows x 256 f32 = 128 KiB per pass
#pragma unroll
        for (int p = 0; p < 2; p++) {
            __syncthreads();
            if (wm == p) {
#pragma unroll
                for (int mf = 0; mf < 8; mf++)
#pragma unroll
                    for (int nf = 0; nf < 4; nf++) {
                        // window-XOR: phys window = (wn*4+nf)^qd -> 2-way banks
                        const int pcol = wn * 64 + ((nf ^ qd) * 16) + ln;
#pragma unroll
                        for (int r = 0; r < 4; r++)
                            Cf[(mf * 16 + qd * 4 + r) * 256 + pcol] = acc[mf][nf][r] + bv[nf];
                    }
            }
            __syncthreads();
#pragma unroll
            for (int q = 0; q < 16; q++) {
                const int c = t + q * 512;
                const int row = c >> 6, cc = c & 63;   // 64 f32x4 chunks/row
                const int gcol = n0 + cc * 4;
                if (gcol < Nvalid)
                    *(f32x4*)&Ct[(size_t)(m0 + p * 128 + row) * Npitch + gcol] =
                        *(const f32x4*)&Cf[row * 256 + ((cc ^ (((row >> 2) & 3) << 2)) * 4)];
            }
        }
    }
}

// ---------------------------------------------------------------------------
// RoPE.  Q: in-place in qkv[s][0..1151], PRE-SCALED by 72^-0.5 * log2(e)
// (softmax scale folded here; flash_attn then uses raw exp2).
// K: -> k_buf [128 nh][1024 l][128] (cols 72..127 zero).
// ---------------------------------------------------------------------------
__global__ void rope_qk(ushort_t* __restrict__ qkv,
                        const float* __restrict__ cosb,
                        const float* __restrict__ sinb,
                        ushort_t* __restrict__ kb)
{
    const int idx = blockIdx.x * 256 + threadIdx.x;   // < 8192*144
    const int d0c = idx % 9;
    const int h = (idx / 9) & 15;
    const int s = idx / 144;
    const int d0 = d0c * 4;
    const int n = s >> 10, l = s & 1023;
    const size_t src = (size_t)s * 3456 + h * 72;
    const size_t dstrow = ((size_t)(n * 16 + h) * 1024 + l) * 128;
    const float SQ = 0.17002325f;   // 72^-0.5 * log2(e)

    f32x4 c1 = *(const f32x4*)&cosb[s * 72 + d0];
    f32x4 c2 = *(const f32x4*)&cosb[s * 72 + d0 + 36];
    f32x4 s1 = *(const f32x4*)&sinb[s * 72 + d0];
    f32x4 s2 = *(const f32x4*)&sinb[s * 72 + d0 + 36];

    {   // Q (in place, pre-scaled)
        us4 x1 = *(const us4*)&qkv[src + d0];
        us4 x2 = *(const us4*)&qkv[src + d0 + 36];
        us4 o1, o2;
#pragma unroll
        for (int j = 0; j < 4; j++) {
            float a = b2f(x1[j]), b = b2f(x2[j]);
            o1[j] = f2b((a * c1[j] - b * s1[j]) * SQ);
            o2[j] = f2b((b * c2[j] + a * s2[j]) * SQ);
        }
        *(us4*)&qkv[src + d0] = o1;
        *(us4*)&qkv[src + d0 + 36] = o2;
    }
    {   // K -> padded k_buf
        us4 x1 = *(const us4*)&qkv[src + 1152 + d0];
        us4 x2 = *(const us4*)&qkv[src + 1152 + d0 + 36];
        us4 o1, o2;
#pragma unroll
        for (int j = 0; j < 4; j++) {
            float a = b2f(x1[j]), b = b2f(x2[j]);
            o1[j] = f2b(a * c1[j] - b * s1[j]);
            o2[j] = f2b(b * c2[j] + a * s2[j]);
        }
        *(us4*)&kb[dstrow + d0] = o1;
        *(us4*)&kb[dstrow + d0 + 36] = o2;
    }
    if (d0c < 7) {   // zero pad cols 72..127 (7 x us8)
        us8 z = (us8){0, 0, 0, 0, 0, 0, 0, 0};
        *(us8*)&kb[dstrow + 72 + d0c * 8] = z;
    }
}

// ---------------------------------------------------------------------------
// V transpose: qkv(bf16)[s][2304+h*72+d] -> Vt [128 nh][80 d][1024 kv]
// (rows d=72..79 zero).  kv order within each 32-kv subtile INTERLEAVED:
// phys slot s holds logical k = (s>>1) + (s&1)*16 (matches packed P-store).
// ---------------------------------------------------------------------------
__global__ void v_transpose(const ushort_t* __restrict__ qkv, ushort_t* __restrict__ vt)
{
    __shared__ short T[64 * 80];
    const int t = threadIdx.x;
    const int nh = blockIdx.x >> 4, kvb = blockIdx.x & 15;
    const int h = nh & 15, n = nh >> 4;
    const int s0 = n * 1024 + kvb * 64;

#pragma unroll
    for (int i = 0; i < 3; i++) {
        int c = t + i * 256;
        if (c < 576) {
            int row = c / 9, off = (c % 9) * 8;
            *(us8*)&T[row * 80 + off] =
                *(const us8*)&qkv[(size_t)(s0 + row) * 3456 + 2304 + h * 72 + off];
        }
    }
    __syncthreads();

#pragma unroll
    for (int i = 0; i < 3; i++) {
        int c = t + i * 256;
        if (c < 640) {
            int d = c >> 3, kc = c & 7;
            us8 o;
            if (d < 72) {
#pragma unroll
                for (int j = 0; j < 8; j++) {
                    int l64 = kc * 8 + j;                 // phys slot in 64-tile
                    int b = l64 >> 5, s = l64 & 31;
                    int kl = (s >> 1) + ((s & 1) << 4);   // logical k in 32-subtile
                    o[j] = (ushort_t)T[(b * 32 + kl) * 80 + d];
                }
            } else {
                o = (us8){0, 0, 0, 0, 0, 0, 0, 0};
            }
            *(us8*)&vt[((size_t)nh * 80 + d) * 1024 + kvb * 64 + kc * 8] = o;
        }
    }
}

// ---------------------------------------------------------------------------
// Flash attention v2: block = (nh, 256-q tile), 4 waves x 64 q-rows each.
// BKV=32.  Static softmax (Q pre-scaled -> exp2), per-lane partial row-sums,
// epilogue reduction.  K/V double-buffered swizzled DMA; Ps pitch 40.
// P-store: interleaved kv pairs packed via explicit RNE + v_perm_b32
// (lo=bf16(p0), hi=bf16(p1)); short-typed store (TBAA) + compiler fence.
// r13: T1 XCD swizzle (512%8==0; groups the 4 same-nh q-tile blocks -- which
// share 416KB K/V -- onto one XCD for L2 reuse) + T5 setprio around the
// QK^T and PV MFMA clusters (2 blocks/CU at independent phases).
// ---------------------------------------------------------------------------
__global__ __launch_bounds__(256, 2) void flash_attn(
    const ushort_t* __restrict__ qkv, const ushort_t* __restrict__ kb,
    const ushort_t* __restrict__ vt, ushort_t* __restrict__ ob)
{
    __shared__ short Ks[2][32 * 128];   // 16384 B  row pitch 256 B
    __shared__ short VtS[2][80 * 32];   // 10240 B  row pitch 64 B
    __shared__ short Ps[4][64 * 40];    // 20480 B  -> total 47104 B

    const int t = threadIdx.x;
    const int lane = t & 63, w = t >> 6;
    const int qd = lane >> 4, ln = lane & 15;
    const int lnx = ln & 7;
    const int lns = (ln >> 1) & 3;
    // XCD-aware bijective swizzle: 512 blocks, 64 per XCD chunk
    const int bid = blockIdx.x;
    const int swz = (bid & 7) * 64 + (bid >> 3);
    const int nh = swz >> 2, qt = swz & 3;
    const int q0 = qt * 256;
    const int h = nh & 15, n = nh >> 4;

    const ushort_t* kbase = kb + (size_t)nh * 1024 * 128;
    const ushort_t* vbase = vt + (size_t)nh * 80 * 1024;

    // ---- Q fragments -> registers.  Wave w owns q rows q0+w*64 .. +63 ----
    bf16x8 qf[4][3];
    {
        const ushort_t* qsrc = qkv + (size_t)(n * 1024 + q0 + w * 64) * 3456 + h * 72;
#pragma unroll
        for (int im = 0; im < 4; im++)
#pragma unroll
            for (int ks = 0; ks < 3; ks++)
                qf[im][ks] = *(const bf16x8*)&qsrc[(size_t)(im * 16 + ln) * 3456 + ks * 32 + qd * 8];
    }

    // ---- prologue: swizzled DMA of kv-tile 0 into buffer 0 ----
#pragma unroll
    for (int i = 0; i < 2; i++) {      // K: 512 chunks (32 rows x 16)
        int c = t + i * 256, r = c >> 4, kc = c & 15;
        gload_lds16(kbase + (size_t)r * 128 + (kc ^ (r & 7)) * 8, &Ks[0][c * 8]);
    }
    {                                   // V: 320 chunks (80 rows x 4)
        int c = t, d = c >> 2, kc = c & 3;
        gload_lds16(vbase + (size_t)d * 1024 + (kc ^ ((d >> 1) & 3)) * 8, &VtS[0][c * 8]);
        if (t < 64) {
            int c2 = t + 256, d2 = c2 >> 2, kc2 = c2 & 3;
            gload_lds16(vbase + (size_t)d2 * 1024 + (kc2 ^ ((d2 >> 1) & 3)) * 8, &VtS[0][c2 * 8]);
        }
    }

    float l_lane[4][4];
    f32x4 acc_o[4][5];
#pragma unroll
    for (int im = 0; im < 4; im++) {
#pragma unroll
        for (int r = 0; r < 4; r++) l_lane[im][r] = 0.f;
#pragma unroll
        for (int jn = 0; jn < 5; jn++) acc_o[im][jn] = (f32x4){0.f, 0.f, 0.f, 0.f};
    }

    for (int it = 0; it < 32; it++) {
        __syncthreads();   // drains DMAs issued last iter; buf^1 free

        if (it < 31) {     // swizzled DMA for kv-tile it+1
            const int nb = (it + 1) & 1;
            const ushort_t* knext = kbase + (size_t)(it + 1) * 4096;
#pragma unroll
            for (int i = 0; i < 2; i++) {
                int c = t + i * 256, r = c >> 4, kc = c & 15;
                gload_lds16(knext + (size_t)r * 128 + (kc ^ (r & 7)) * 8, &Ks[nb][c * 8]);
            }
            const ushort_t* vnext = vbase + (it + 1) * 32;
            {
                int c = t, d = c >> 2, kc = c & 3;
                gload_lds16(vnext + (size_t)d * 1024 + (kc ^ ((d >> 1) & 3)) * 8, &VtS[nb][c * 8]);
                if (t < 64) {
                    int c2 = t + 256, d2 = c2 >> 2, kc2 = c2 & 3;
                    gload_lds16(vnext + (size_t)d2 * 1024 + (kc2 ^ ((d2 >> 1) & 3)) * 8, &VtS[nb][c2 * 8]);
                }
            }
        }

        const short* KsB = Ks[it & 1];
        const short* VtB = VtS[it & 1];

        // ---- Q K^T ----  24 MFMA (4 im x 2 jk x 3 ks)
        f32x4 sc[4][2];
#pragma unroll
        for (int im = 0; im < 4; im++)
#pragma unroll
            for (int jk = 0; jk < 2; jk++) sc[im][jk] = (f32x4){0.f, 0.f, 0.f, 0.f};
        __builtin_amdgcn_s_setprio(1);
#pragma unroll
        for (int ks = 0; ks < 3; ks++) {
            const int m = ks * 4 + qd;
#pragma unroll
            for (int jk = 0; jk < 2; jk++) {
                bf16x8 bfr = *(const bf16x8*)&KsB[(jk * 16 + ln) * 128 + (m ^ lnx) * 8];
#pragma unroll
                for (int im = 0; im < 4; im++)
                    sc[im][jk] = __builtin_amdgcn_mfma_f32_16x16x32_bf16(
                        qf[im][ks], bfr, sc[im][jk], 0, 0, 0);
            }
        }
        __builtin_amdgcn_s_setprio(0);

        // ---- static softmax: p = exp2(sc); explicit RNE pair pack ----
#pragma unroll
        for (int im = 0; im < 4; im++) {
#pragma unroll
            for (int r = 0; r < 4; r++) {
                float p0 = EXP2F(sc[im][0][r]);
                float p1 = EXP2F(sc[im][1][r]);
                l_lane[im][r] += p0 + p1;
                union { float f; unsigned int i; } u0, u1;
                u0.f = p0; u1.f = p1;
                unsigned int r0 = u0.i + 0x7fffu + ((u0.i >> 16) & 1u);
                unsigned int r1 = u1.i + 0x7fffu + ((u1.i >> 16) & 1u);
                // lo16 = r0>>16 = bf16(p0), hi16 = r1>>16 = bf16(p1)
                unsigned int pk = __builtin_amdgcn_perm(r1, r0, 0x07060302u);
                union { unsigned int u; s16x2 v; } cv; cv.u = pk;
                *(s16x2*)((char*)&Ps[w][0] + (im * 16 + qd * 4 + r) * 80 + ln * 4) = cv.v;
            }
        }
        asm volatile("" ::: "memory");   // pin P-stores before PV ds_reads

        // ---- P V ----  20 MFMA (4 im x 5 jn), single K=32 pass
        __builtin_amdgcn_s_setprio(1);
#pragma unroll
        for (int jn = 0; jn < 5; jn++) {
            bf16x8 vf = *(const bf16x8*)&VtB[(jn * 16 + ln) * 32 + (qd ^ lns) * 8];
#pragma unroll
            for (int im = 0; im < 4; im++) {
                bf16x8 pf = *(const bf16x8*)&Ps[w][(im * 16 + ln) * 40 + qd * 8];
                acc_o[im][jn] = __builtin_amdgcn_mfma_f32_16x16x32_bf16(
                    pf, vf, acc_o[im][jn], 0, 0, 0);
            }
        }
        __builtin_amdgcn_s_setprio(0);
    }

    // ---- epilogue: reduce l across the 16-lane group, normalize, store ----
    const size_t obase = ((size_t)(n * 1024 + q0 + w * 64)) * 1152 + h * 72;
#pragma unroll
    for (int im = 0; im < 4; im++) {
#pragma unroll
        for (int r = 0; r < 4; r++) {
            float l = l_lane[im][r];
            l += __shfl_xor(l, 1);
            l += __shfl_xor(l, 2);
            l += __shfl_xor(l, 4);
            l += __shfl_xor(l, 8);
            const float inv = 1.0f / l;
            const int rowl = im * 16 + qd * 4 + r;
#pragma unroll
            for (int jn = 0; jn < 5; jn++) {
                const int d = jn * 16 + ln;
                if (d < 72)
                    ob[obase + (size_t)rowl * 1152 + d] = f2b(acc_o[im][jn][r] * inv);
            }
        }
    }
}

// ---------------------------------------------------------------------------
extern "C" void kernel_launch(void* const* d_in, const int* in_sizes, int n_in,
                              void* d_out, int out_size, void* d_ws, size_t ws_size,
                              hipStream_t stream)
{
    const float* hs     = (const float*)d_in[0];
    const float* cosb   = (const float*)d_in[1];
    const float* sinb   = (const float*)d_in[2];
    const float* qkv_w  = (const float*)d_in[3];
    const float* qkv_b  = (const float*)d_in[4];
    const float* proj_w = (const float*)d_in[5];
    const float* proj_b = (const float*)d_in[6];

    char* ws = (char*)d_ws;
    // hidden_bf16 (dead after gemm1) aliases attn (written by flash_attn)
    ushort_t* hs_bf   = (ushort_t*)(ws);                //  8192*1152*2 = 18,874,368
    ushort_t* attn    = (ushort_t*)(ws);                //  aliases hs_bf
    ushort_t* qkvw_bf = (ushort_t*)(ws + 18874368);     //  3456*1152*2 =  7,962,624
    ushort_t* projw_bf= (ushort_t*)(ws + 26836992);     //  1152*1152*2 =  2,654,208
    ushort_t* qkv_tmp = (ushort_t*)(ws + 29491200);     //  8192*3456*2 = 56,623,104
    ushort_t* k_buf   = (ushort_t*)(ws + 86114304);     //  128*1024*128*2 = 33,554,432
    ushort_t* v_t     = (ushort_t*)(ws + 119668736);    //  128*80*1024*2  = 20,971,520
    float*    out     = (float*)d_out;                  //  total ws: 140,640,256 B

    // fused fp32->bf16 converts: 1179648 + 497664 + 165888 = 1843200 = 7200*256
    cvt3_f32_bf16<<<7200, 256, 0, stream>>>(hs, hs_bf, 1179648,
                                            qkv_w, qkvw_bf, 497664,
                                            proj_w, projw_bf, 165888);

    // QKV GEMM: M=8192, N=3456 (14 x 256 tiles, last masked), K=1152
    gemm256_bt_bias<false><<<dim3(14, 32), 512, 0, stream>>>(hs_bf, qkvw_bf, qkv_b, qkv_tmp, 1152, 3456, 3456);
    rope_qk<<<4608, 256, 0, stream>>>(qkv_tmp, cosb, sinb, k_buf);
    v_transpose<<<2048, 256, 0, stream>>>(qkv_tmp, v_t);
    flash_attn<<<512, 256, 0, stream>>>(qkv_tmp, k_buf, v_t, attn);
    // proj GEMM on the 256-tile structure: M=8192, N=1152 (5 tiles, last
    // masked; B-overread lands in mapped qkv_tmp), K=1152, f32 out.
    gemm256_bt_bias<true><<<dim3(5, 32), 512, 0, stream>>>(attn, projw_bf, proj_b, out, 1152, 1152, 1152);
}